// Round 1
// baseline (823.258 us; speedup 1.0000x reference)
//
#include <hip/hip_runtime.h>

// ---------------------------------------------------------------------------
// LabeledConv: 4x GCNConv(256->256) + masked-feature epilogue, MI355X gfx950.
// Pipeline:
//   1. hist/dis: in-degree per edge set (+1 self loop), dis = rsqrt(deg)
//   2. CSR build: exclusive scan of hist -> row_ptr; fill sorted payload
//      {src, norm=dis[src]*dis[dst]} per target node (avoids 512M f32 atomics)
//   3. Wcat^T prep: fold p_{k+2} into W_k columns, store transposed bf16
//   4. x -> bf16
//   5. GEMM H' = xb @ Wcat  (N x 256 x 1024, bf16 MFMA 16x16x32)
//   6. Aggregate: per node (1 wave/node): self-loop + CSR edges, gather H'
//      rows, fuse epilogue (t0/t1 * x[:,0] * p0/p1 + sum_k b_k*p_{k+2})
// ---------------------------------------------------------------------------

typedef __bf16 v8bf __attribute__((ext_vector_type(8)));
typedef float v4f __attribute__((ext_vector_type(4)));

__device__ __forceinline__ unsigned short f2bf(float f) {
  unsigned u = __float_as_uint(f);
  u += 0x7fffu + ((u >> 16) & 1u);  // RNE
  return (unsigned short)(u >> 16);
}
__device__ __forceinline__ float bf2f(unsigned short s) {
  return __uint_as_float(((unsigned)s) << 16);
}
__device__ __forceinline__ void async_ld16(const void* g, void* l) {
  __builtin_amdgcn_global_load_lds((__attribute__((address_space(1))) void*)g,
                                   (__attribute__((address_space(3))) void*)l,
                                   16, 0, 0);
}

// ---------------------------------------------------------------------------
__global__ void lc_zero(int* __restrict__ p, int n) {
  int i = blockIdx.x * 256 + threadIdx.x;
  if (i < n) p[i] = 0;
}

__global__ void lc_hist(const int* __restrict__ e0, const int* __restrict__ e1,
                        const int* __restrict__ e2, const int* __restrict__ e3,
                        int* __restrict__ hist, int N, int E) {
  int e = blockIdx.x * 256 + threadIdx.x;
  if (e >= E) return;
  int k = blockIdx.y;
  const int* ed = (k == 0) ? e0 : (k == 1) ? e1 : (k == 2) ? e2 : e3;
  int col = ed[E + e];  // target
  atomicAdd(&hist[k * N + col], 1);
}

__global__ void lc_dis(const int* __restrict__ hist, float* __restrict__ dis, int M) {
  int i = blockIdx.x * 256 + threadIdx.x;
  if (i < M) dis[i] = rsqrtf((float)(hist[i] + 1));  // +1 self loop
}

// exclusive scan: per-block (256) + block sums
__global__ void lc_scan1(const int* __restrict__ in, int* __restrict__ outp,
                         int* __restrict__ bsum, int M) {
  __shared__ int tmp[256];
  int t = threadIdx.x, i = blockIdx.x * 256 + t;
  int v = (i < M) ? in[i] : 0;
  tmp[t] = v;
  __syncthreads();
  for (int off = 1; off < 256; off <<= 1) {
    int add = (t >= off) ? tmp[t - off] : 0;
    __syncthreads();
    tmp[t] += add;
    __syncthreads();
  }
  if (i < M) outp[i] = tmp[t] - v;
  if (t == 255) bsum[blockIdx.x] = tmp[255];
}

__global__ void lc_scan2(int* __restrict__ bsum, int nb) {
  __shared__ int tmp[256];
  __shared__ int carry_s;
  int t = threadIdx.x;
  if (t == 0) carry_s = 0;
  __syncthreads();
  for (int base = 0; base < nb; base += 256) {
    int i = base + t;
    int v = (i < nb) ? bsum[i] : 0;
    tmp[t] = v;
    __syncthreads();
    for (int off = 1; off < 256; off <<= 1) {
      int add = (t >= off) ? tmp[t - off] : 0;
      __syncthreads();
      tmp[t] += add;
      __syncthreads();
    }
    int carry = carry_s;
    int total = tmp[255];
    if (i < nb) bsum[i] = carry + tmp[t] - v;
    __syncthreads();
    if (t == 0) carry_s = carry + total;
    __syncthreads();
  }
}

__global__ void lc_scan3(int* __restrict__ rp, int* __restrict__ cursor,
                         const int* __restrict__ bsum, int M) {
  int i = blockIdx.x * 256 + threadIdx.x;
  if (i < M) {
    int v = rp[i] + bsum[blockIdx.x];
    rp[i] = v;
    cursor[i] = v;
  }
}

__global__ void lc_fill(const int* __restrict__ e0, const int* __restrict__ e1,
                        const int* __restrict__ e2, const int* __restrict__ e3,
                        int* __restrict__ cursor, const float* __restrict__ dis,
                        int2* __restrict__ payload, int N, int E) {
  int e = blockIdx.x * 256 + threadIdx.x;
  if (e >= E) return;
  int k = blockIdx.y;
  const int* ed = (k == 0) ? e0 : (k == 1) ? e1 : (k == 2) ? e2 : e3;
  int src = ed[e], col = ed[E + e];
  int pos = atomicAdd(&cursor[k * N + col], 1);
  float nrm = dis[k * N + src] * dis[k * N + col];
  payload[pos] = make_int2(src, __float_as_int(nrm));
}

__global__ void lc_bias(const float* __restrict__ b1, const float* __restrict__ b2,
                        const float* __restrict__ b3, const float* __restrict__ b4,
                        const float* __restrict__ p2, const float* __restrict__ p3,
                        const float* __restrict__ p4, const float* __restrict__ p5,
                        float* __restrict__ biasc) {
  int c = threadIdx.x;
  biasc[c] = b1[c] * p2[c] + b2[c] * p3[c] + b3[c] * p4[c] + b4[c] * p5[c];
}

// WcatT[c_out][kk] = W_k[kk][c] * p_{k+2}[c], c_out = k*256 + c  (bf16)
__global__ void lc_prep(const float* __restrict__ W1, const float* __restrict__ W2,
                        const float* __restrict__ W3, const float* __restrict__ W4,
                        const float* __restrict__ p2, const float* __restrict__ p3,
                        const float* __restrict__ p4, const float* __restrict__ p5,
                        unsigned short* __restrict__ Wt) {
  int co = blockIdx.x, kk = threadIdx.x;
  int k = co >> 8, c = co & 255;
  const float* W = (k == 0) ? W1 : (k == 1) ? W2 : (k == 2) ? W3 : W4;
  const float* p = (k == 0) ? p2 : (k == 1) ? p3 : (k == 2) ? p4 : p5;
  Wt[co * 256 + kk] = f2bf(W[kk * 256 + c] * p[c]);
}

__global__ void lc_cvt(const float4* __restrict__ x4, ushort4* __restrict__ xb4, int n4) {
  int i = blockIdx.x * 256 + threadIdx.x;
  if (i >= n4) return;
  float4 v = x4[i];
  ushort4 r;
  r.x = f2bf(v.x); r.y = f2bf(v.y); r.z = f2bf(v.z); r.w = f2bf(v.w);
  xb4[i] = r;
}

// ---------------------------------------------------------------------------
// GEMM: H'[M x width] = xb[M x 256] @ Wcat[256 x width], bf16 in/out, f32 acc.
// 128x128 tile, BK=32, 256 threads = 4 waves (2x2 of 64x64), single-buffered
// LDS staged via global_load_lds width=16. Wt is transposed: Wt[n][k].
__global__ __launch_bounds__(256) void lc_gemm(
    const unsigned short* __restrict__ xb, const unsigned short* __restrict__ Wt,
    unsigned short* __restrict__ Hp, int Mrows, int width) {
  __shared__ alignas(16) unsigned short As[128 * 32];
  __shared__ alignas(16) unsigned short Bs[128 * 32];
  int t = threadIdx.x;
  int w = t >> 6, lane = t & 63;
  int wm = w & 1, wn = w >> 1;
  int quad = lane >> 4, l16 = lane & 15;
  int row0 = blockIdx.x * 128, col0 = blockIdx.y * 128;

  v4f acc[4][4];
#pragma unroll
  for (int mt = 0; mt < 4; mt++)
#pragma unroll
    for (int nt = 0; nt < 4; nt++) {
      v4f z = {0.f, 0.f, 0.f, 0.f};
      acc[mt][nt] = z;
    }

  for (int kk = 0; kk < 256; kk += 32) {
#pragma unroll
    for (int p = 0; p < 2; p++) {
      int cbase = p * 256 + w * 64;        // wave-uniform chunk base
      int cA = cbase + lane;               // this lane's 16B chunk
      int rl = cA >> 2, c16 = cA & 3;      // row 0..127, 16B-piece 0..3
      int grow = row0 + rl;
      if (grow >= Mrows) grow = Mrows - 1; // clamp tail (stores are guarded)
      async_ld16(xb + (size_t)grow * 256 + kk + c16 * 8, &As[cbase * 8]);
      async_ld16(Wt + (size_t)(col0 + rl) * 256 + kk + c16 * 8, &Bs[cbase * 8]);
    }
    __syncthreads();  // drains vmcnt (global_load_lds) + barrier

    v8bf af[4], bfr[4];
#pragma unroll
    for (int mt = 0; mt < 4; mt++) {
      int r = wm * 64 + mt * 16 + l16;
      af[mt] = *(const v8bf*)&As[r * 32 + quad * 8];
    }
#pragma unroll
    for (int nt = 0; nt < 4; nt++) {
      int n = wn * 64 + nt * 16 + l16;
      bfr[nt] = *(const v8bf*)&Bs[n * 32 + quad * 8];
    }
#pragma unroll
    for (int mt = 0; mt < 4; mt++)
#pragma unroll
      for (int nt = 0; nt < 4; nt++)
        acc[mt][nt] =
            __builtin_amdgcn_mfma_f32_16x16x32_bf16(af[mt], bfr[nt], acc[mt][nt], 0, 0, 0);
    __syncthreads();
  }

  // C/D layout: col = lane&15, row = quad*4 + reg  (m89/m91-verified)
#pragma unroll
  for (int mt = 0; mt < 4; mt++) {
    int growb = row0 + wm * 64 + mt * 16 + quad * 4;
#pragma unroll
    for (int nt = 0; nt < 4; nt++) {
      int gcol = col0 + wn * 64 + nt * 16 + l16;
#pragma unroll
      for (int r = 0; r < 4; r++) {
        int grow = growb + r;
        if (grow < Mrows) Hp[(size_t)grow * width + gcol] = f2bf(acc[mt][nt][r]);
      }
    }
  }
}

// ---------------------------------------------------------------------------
// Aggregation: 1 wave per node, lane owns 4 channels (c = lane*4).
// out[n] = sum_k ( H'_k[n]/deg_k[n] + sum_{e: col=n} H'_k[src_e]*norm_e )
//          [+ prev out] [+ epilogue]
__global__ __launch_bounds__(256) void lc_agg(
    const unsigned short* __restrict__ Hp, int Hwidth, int k0, int k1,
    int addprev, int doepi, const int* __restrict__ rp, const int* __restrict__ hist,
    const float* __restrict__ dis, const int2* __restrict__ payload,
    const float* __restrict__ x, const float* __restrict__ t0,
    const float* __restrict__ t1, const float* __restrict__ p0,
    const float* __restrict__ p1, const float* __restrict__ biasc,
    float* __restrict__ out, int N) {
  int t = threadIdx.x;
  int w = t >> 6, lane = t & 63;
  int n = blockIdx.x * 4 + w;
  if (n >= N) return;
  int c = lane * 4;

  float a0 = 0.f, a1 = 0.f, a2 = 0.f, a3 = 0.f;
  for (int k = k0; k < k1; k++) {
    int koff = (k - k0) * 256;
    float dn = dis[k * N + n];
    float s = dn * dn;  // self-loop norm = 1/deg
    ushort4 hv = *(const ushort4*)&Hp[(size_t)n * Hwidth + koff + c];
    a0 += bf2f(hv.x) * s; a1 += bf2f(hv.y) * s;
    a2 += bf2f(hv.z) * s; a3 += bf2f(hv.w) * s;
    int start = rp[k * N + n];
    int cnt = hist[k * N + n];
    for (int i = 0; i < cnt; i++) {
      int2 pl = payload[start + i];
      int src = pl.x;
      float nrm = __int_as_float(pl.y);
      ushort4 g = *(const ushort4*)&Hp[(size_t)src * Hwidth + koff + c];
      a0 += bf2f(g.x) * nrm; a1 += bf2f(g.y) * nrm;
      a2 += bf2f(g.z) * nrm; a3 += bf2f(g.w) * nrm;
    }
  }
  float4 res = make_float4(a0, a1, a2, a3);
  if (addprev) {
    float4 prev = *(const float4*)&out[(size_t)n * 256 + c];
    res.x += prev.x; res.y += prev.y; res.z += prev.z; res.w += prev.w;
  }
  if (doepi) {
    float xc = x[(size_t)n * 256];
    float m0 = t0[n] * xc, m1 = t1[n] * xc;
    float4 q0 = *(const float4*)&p0[c];
    float4 q1 = *(const float4*)&p1[c];
    float4 bc = *(const float4*)&biasc[c];
    res.x += m0 * q0.x + m1 * q1.x + bc.x;
    res.y += m0 * q0.y + m1 * q1.y + bc.y;
    res.z += m0 * q0.z + m1 * q1.z + bc.z;
    res.w += m0 * q0.w + m1 * q1.w + bc.w;
  }
  *(float4*)&out[(size_t)n * 256 + c] = res;
}

// ---------------------------------------------------------------------------
extern "C" void kernel_launch(void* const* d_in, const int* in_sizes, int n_in,
                              void* d_out, int out_size, void* d_ws, size_t ws_size,
                              hipStream_t stream) {
  const float* x = (const float*)d_in[0];
  const int* e00 = (const int*)d_in[1];
  const int* e01 = (const int*)d_in[2];
  const int* e10 = (const int*)d_in[3];
  const int* e11 = (const int*)d_in[4];
  const float* t0 = (const float*)d_in[5];
  const float* t1 = (const float*)d_in[6];
  const float* W1 = (const float*)d_in[7];
  const float* b1 = (const float*)d_in[8];
  const float* W2 = (const float*)d_in[9];
  const float* b2 = (const float*)d_in[10];
  const float* W3 = (const float*)d_in[11];
  const float* b3 = (const float*)d_in[12];
  const float* W4 = (const float*)d_in[13];
  const float* b4 = (const float*)d_in[14];
  const float* p0 = (const float*)d_in[15];
  const float* p1 = (const float*)d_in[16];
  const float* p2 = (const float*)d_in[17];
  const float* p3 = (const float*)d_in[18];
  const float* p4 = (const float*)d_in[19];
  const float* p5 = (const float*)d_in[20];
  float* out = (float*)d_out;

  int N = in_sizes[0] / 256;
  int E = in_sizes[1] / 2;
  int M4 = 4 * N;
  int nb = (M4 + 255) / 256;

  // workspace carve (256B-aligned)
  char* wp = (char*)d_ws;
  auto carve = [&](size_t bytes) {
    void* r = (void*)wp;
    wp += (bytes + 255) & ~(size_t)255;
    return r;
  };
  unsigned short* xb = (unsigned short*)carve((size_t)N * 256 * 2);
  unsigned short* Wt = (unsigned short*)carve(1024 * 256 * 2);
  int* hist = (int*)carve((size_t)M4 * 4);
  float* dis = (float*)carve((size_t)M4 * 4);
  int* rp = (int*)carve((size_t)M4 * 4);
  int* cursor = (int*)carve((size_t)M4 * 4);
  int* bsum = (int*)carve((size_t)nb * 4);
  float* biasc = (float*)carve(256 * 4);
  int2* payload = (int2*)carve((size_t)4 * E * 8);
  size_t used = (size_t)(wp - (char*)d_ws);
  size_t remain = (ws_size > used) ? ws_size - used : 0;
  bool fat = remain >= (size_t)N * 1024 * 2;
  unsigned short* Hp = (unsigned short*)wp;  // fat: N x 1024; lean: N x 256 reused

  int gE = (E + 255) / 256;
  int gM = (M4 + 255) / 256;

  lc_zero<<<gM, 256, 0, stream>>>(hist, M4);
  lc_hist<<<dim3(gE, 4), 256, 0, stream>>>(e00, e01, e10, e11, hist, N, E);
  lc_dis<<<gM, 256, 0, stream>>>(hist, dis, M4);
  lc_scan1<<<nb, 256, 0, stream>>>(hist, rp, bsum, M4);
  lc_scan2<<<1, 256, 0, stream>>>(bsum, nb);
  lc_scan3<<<nb, 256, 0, stream>>>(rp, cursor, bsum, M4);
  lc_fill<<<dim3(gE, 4), 256, 0, stream>>>(e00, e01, e10, e11, cursor, dis, payload, N, E);
  lc_bias<<<1, 256, 0, stream>>>(b1, b2, b3, b4, p2, p3, p4, p5, biasc);
  lc_prep<<<1024, 256, 0, stream>>>(W1, W2, W3, W4, p2, p3, p4, p5, Wt);
  lc_cvt<<<(N * 64 + 255) / 256, 256, 0, stream>>>((const float4*)x, (ushort4*)xb, N * 64);

  int gemm_mb = (N + 127) / 128;
  if (fat) {
    lc_gemm<<<dim3(gemm_mb, 8), 256, 0, stream>>>(xb, Wt, Hp, N, 1024);
    lc_agg<<<(N + 3) / 4, 256, 0, stream>>>(Hp, 1024, 0, 4, 0, 1, rp, hist, dis,
                                            payload, x, t0, t1, p0, p1, biasc, out, N);
  } else {
    for (int k = 0; k < 4; k++) {
      lc_gemm<<<dim3(gemm_mb, 2), 256, 0, stream>>>(xb, Wt + (size_t)k * 65536, Hp, N, 256);
      lc_agg<<<(N + 3) / 4, 256, 0, stream>>>(Hp, 256, k, k + 1, (k > 0) ? 1 : 0,
                                              (k == 3) ? 1 : 0, rp, hist, dis,
                                              payload, x, t0, t1, p0, p1, biasc, out, N);
    }
  }
}

// Round 2
// 720.627 us; speedup vs baseline: 1.1424x; 1.1424x over previous
//
#include <hip/hip_runtime.h>

// ---------------------------------------------------------------------------
// LabeledConv round 2: aggregate-then-GEMM (linearity swap).
//   out = [Agg0(xb)|Agg1(xb)|Agg2(xb)|Agg3(xb)] @ [W'1;W'2;W'3;W'4] + epilogue
// Agg gathers from xb (51 MB, LLC-resident) instead of H' (205 MB, HBM) —
// kills the 633 MB HBM gather traffic of round 1's lc_agg. Epilogue fused
// into GEMM (single f32 write of out).
// ---------------------------------------------------------------------------

typedef __bf16 v8bf __attribute__((ext_vector_type(8)));
typedef float v4f __attribute__((ext_vector_type(4)));

__device__ __forceinline__ unsigned short f2bf(float f) {
  unsigned u = __float_as_uint(f);
  u += 0x7fffu + ((u >> 16) & 1u);  // RNE
  return (unsigned short)(u >> 16);
}
__device__ __forceinline__ float bf2f(unsigned short s) {
  return __uint_as_float(((unsigned)s) << 16);
}
__device__ __forceinline__ void async_ld16(const void* g, void* l) {
  __builtin_amdgcn_global_load_lds((__attribute__((address_space(1))) void*)g,
                                   (__attribute__((address_space(3))) void*)l,
                                   16, 0, 0);
}

// ---------------------------------------------------------------------------
__global__ void lc_zero(int* __restrict__ p, int n) {
  int i = blockIdx.x * 256 + threadIdx.x;
  if (i < n) p[i] = 0;
}

__global__ void lc_hist(const int* __restrict__ e0, const int* __restrict__ e1,
                        const int* __restrict__ e2, const int* __restrict__ e3,
                        int* __restrict__ hist, int N, int E) {
  int e = blockIdx.x * 256 + threadIdx.x;
  if (e >= E) return;
  int k = blockIdx.y;
  const int* ed = (k == 0) ? e0 : (k == 1) ? e1 : (k == 2) ? e2 : e3;
  int col = ed[E + e];
  atomicAdd(&hist[k * N + col], 1);
}

__global__ void lc_dis(const int* __restrict__ hist, float* __restrict__ dis, int M) {
  int i = blockIdx.x * 256 + threadIdx.x;
  if (i < M) dis[i] = rsqrtf((float)(hist[i] + 1));  // +1 self loop
}

__global__ void lc_scan1(const int* __restrict__ in, int* __restrict__ outp,
                         int* __restrict__ bsum, int M) {
  __shared__ int tmp[256];
  int t = threadIdx.x, i = blockIdx.x * 256 + t;
  int v = (i < M) ? in[i] : 0;
  tmp[t] = v;
  __syncthreads();
  for (int off = 1; off < 256; off <<= 1) {
    int add = (t >= off) ? tmp[t - off] : 0;
    __syncthreads();
    tmp[t] += add;
    __syncthreads();
  }
  if (i < M) outp[i] = tmp[t] - v;
  if (t == 255) bsum[blockIdx.x] = tmp[255];
}

__global__ void lc_scan2(int* __restrict__ bsum, int nb) {
  __shared__ int tmp[256];
  __shared__ int carry_s;
  int t = threadIdx.x;
  if (t == 0) carry_s = 0;
  __syncthreads();
  for (int base = 0; base < nb; base += 256) {
    int i = base + t;
    int v = (i < nb) ? bsum[i] : 0;
    tmp[t] = v;
    __syncthreads();
    for (int off = 1; off < 256; off <<= 1) {
      int add = (t >= off) ? tmp[t - off] : 0;
      __syncthreads();
      tmp[t] += add;
      __syncthreads();
    }
    int carry = carry_s;
    int total = tmp[255];
    if (i < nb) bsum[i] = carry + tmp[t] - v;
    __syncthreads();
    if (t == 0) carry_s = carry + total;
    __syncthreads();
  }
}

__global__ void lc_scan3(int* __restrict__ rp, int* __restrict__ cursor,
                         const int* __restrict__ bsum, int M) {
  int i = blockIdx.x * 256 + threadIdx.x;
  if (i < M) {
    int v = rp[i] + bsum[blockIdx.x];
    rp[i] = v;
    cursor[i] = v;
  }
}

__global__ void lc_fill(const int* __restrict__ e0, const int* __restrict__ e1,
                        const int* __restrict__ e2, const int* __restrict__ e3,
                        int* __restrict__ cursor, const float* __restrict__ dis,
                        int2* __restrict__ payload, int N, int E) {
  int e = blockIdx.x * 256 + threadIdx.x;
  if (e >= E) return;
  int k = blockIdx.y;
  const int* ed = (k == 0) ? e0 : (k == 1) ? e1 : (k == 2) ? e2 : e3;
  int src = ed[e], col = ed[E + e];
  int pos = atomicAdd(&cursor[k * N + col], 1);
  float nrm = dis[k * N + src] * dis[k * N + col];
  payload[pos] = make_int2(src, __float_as_int(nrm));
}

__global__ void lc_bias(const float* __restrict__ b1, const float* __restrict__ b2,
                        const float* __restrict__ b3, const float* __restrict__ b4,
                        const float* __restrict__ p2, const float* __restrict__ p3,
                        const float* __restrict__ p4, const float* __restrict__ p5,
                        float* __restrict__ biasc) {
  int c = threadIdx.x;
  biasc[c] = b1[c] * p2[c] + b2[c] * p3[c] + b3[c] * p4[c] + b4[c] * p5[c];
}

// Wt[co][k*256+kk] = W_k[kk][co] * p_{k+2}[co]  (B operand, rows=out chan, K=1024)
__global__ void lc_prep(const float* __restrict__ W1, const float* __restrict__ W2,
                        const float* __restrict__ W3, const float* __restrict__ W4,
                        const float* __restrict__ p2, const float* __restrict__ p3,
                        const float* __restrict__ p4, const float* __restrict__ p5,
                        unsigned short* __restrict__ Wt) {
  int b = blockIdx.x;
  int k = b >> 8, co = b & 255;
  int kk = threadIdx.x;
  const float* W = (k == 0) ? W1 : (k == 1) ? W2 : (k == 2) ? W3 : W4;
  const float* p = (k == 0) ? p2 : (k == 1) ? p3 : (k == 2) ? p4 : p5;
  Wt[(size_t)co * 1024 + k * 256 + kk] = f2bf(W[kk * 256 + co] * p[co]);
}

// x -> bf16; also m0[n]=t0[n]*x[n,0], m1[n]=t1[n]*x[n,0]
__global__ void lc_cvt(const float4* __restrict__ x4, ushort4* __restrict__ xb4,
                       const float* __restrict__ t0, const float* __restrict__ t1,
                       float* __restrict__ m0, float* __restrict__ m1, int n4) {
  int i = blockIdx.x * 256 + threadIdx.x;
  if (i >= n4) return;
  float4 v = x4[i];
  ushort4 r;
  r.x = f2bf(v.x); r.y = f2bf(v.y); r.z = f2bf(v.z); r.w = f2bf(v.w);
  xb4[i] = r;
  if ((i & 63) == 0) {
    int n = i >> 6;
    float xc = v.x;
    m0[n] = t0[n] * xc;
    m1[n] = t1[n] * xc;
  }
}

// ---------------------------------------------------------------------------
// Aggregate raw xb per edge set. 1 wave per (node,k); lane owns 4 channels.
// kcount==4 (fat): n=blockIdx.x, k=wave -> Agg[n][k*256+c], aggw=1024
// kcount==1 (lean): n=blockIdx.x*4+wave, k=kbase -> Agg[n][c], aggw=256
// Edge loop unrolled x4: 4 independent gathers in flight per wave.
__global__ __launch_bounds__(256) void lc_aggx(
    const unsigned short* __restrict__ xb, unsigned short* __restrict__ Agg,
    int aggw, int kcount, int kbase, const int* __restrict__ rp,
    const int* __restrict__ hist, const float* __restrict__ dis,
    const int2* __restrict__ payload, int N) {
  int t = threadIdx.x;
  int w = t >> 6, lane = t & 63;
  int n, k, koff;
  if (kcount == 4) { n = blockIdx.x; k = w; koff = k * 256; }
  else { n = blockIdx.x * 4 + w; k = kbase; koff = 0; }
  if (n >= N) return;
  int c = lane * 4;
  int idx = k * N + n;

  float dn = dis[idx];
  float s = dn * dn;  // self-loop norm = 1/deg
  ushort4 hv = *(const ushort4*)&xb[(size_t)n * 256 + c];
  float a0 = bf2f(hv.x) * s, a1 = bf2f(hv.y) * s;
  float a2 = bf2f(hv.z) * s, a3 = bf2f(hv.w) * s;

  int start = rp[idx];
  int cnt = hist[idx];
  int i = 0;
  for (; i + 4 <= cnt; i += 4) {
    int2 e0 = payload[start + i];
    int2 e1 = payload[start + i + 1];
    int2 e2 = payload[start + i + 2];
    int2 e3 = payload[start + i + 3];
    ushort4 g0 = *(const ushort4*)&xb[(size_t)e0.x * 256 + c];
    ushort4 g1 = *(const ushort4*)&xb[(size_t)e1.x * 256 + c];
    ushort4 g2 = *(const ushort4*)&xb[(size_t)e2.x * 256 + c];
    ushort4 g3 = *(const ushort4*)&xb[(size_t)e3.x * 256 + c];
    float n0 = __int_as_float(e0.y), n1 = __int_as_float(e1.y);
    float n2 = __int_as_float(e2.y), n3 = __int_as_float(e3.y);
    a0 += bf2f(g0.x) * n0 + bf2f(g1.x) * n1 + bf2f(g2.x) * n2 + bf2f(g3.x) * n3;
    a1 += bf2f(g0.y) * n0 + bf2f(g1.y) * n1 + bf2f(g2.y) * n2 + bf2f(g3.y) * n3;
    a2 += bf2f(g0.z) * n0 + bf2f(g1.z) * n1 + bf2f(g2.z) * n2 + bf2f(g3.z) * n3;
    a3 += bf2f(g0.w) * n0 + bf2f(g1.w) * n1 + bf2f(g2.w) * n2 + bf2f(g3.w) * n3;
  }
  for (; i < cnt; i++) {
    int2 e0 = payload[start + i];
    ushort4 g0 = *(const ushort4*)&xb[(size_t)e0.x * 256 + c];
    float n0 = __int_as_float(e0.y);
    a0 += bf2f(g0.x) * n0;
    a1 += bf2f(g0.y) * n0;
    a2 += bf2f(g0.z) * n0;
    a3 += bf2f(g0.w) * n0;
  }
  ushort4 r;
  r.x = f2bf(a0); r.y = f2bf(a1); r.z = f2bf(a2); r.w = f2bf(a3);
  *(ushort4*)&Agg[(size_t)n * aggw + koff + c] = r;
}

// ---------------------------------------------------------------------------
// GEMM: out[M x 256] (+)= A[M x K]bf16 @ B^T[256 x K]bf16, f32 out, fused
// epilogue (m0*p0 + m1*p1 + biasc). 128x128 tile, BK=32, 4 waves (2x2).
__global__ __launch_bounds__(256) void lc_gemm(
    const unsigned short* __restrict__ A, int strideA,
    const unsigned short* __restrict__ B, int strideB, int K,
    float* __restrict__ out, int Mrows, int addprev, int doepi,
    const float* __restrict__ m0, const float* __restrict__ m1,
    const float* __restrict__ p0, const float* __restrict__ p1,
    const float* __restrict__ biasc) {
  __shared__ alignas(16) unsigned short As[128 * 32];
  __shared__ alignas(16) unsigned short Bs[128 * 32];
  int t = threadIdx.x;
  int w = t >> 6, lane = t & 63;
  int wm = w & 1, wn = w >> 1;
  int quad = lane >> 4, l16 = lane & 15;
  int row0 = blockIdx.x * 128, col0 = blockIdx.y * 128;

  v4f acc[4][4];
#pragma unroll
  for (int mt = 0; mt < 4; mt++)
#pragma unroll
    for (int nt = 0; nt < 4; nt++) {
      v4f z = {0.f, 0.f, 0.f, 0.f};
      acc[mt][nt] = z;
    }

  for (int kk = 0; kk < K; kk += 32) {
#pragma unroll
    for (int p = 0; p < 2; p++) {
      int cbase = p * 256 + w * 64;
      int cA = cbase + lane;
      int rl = cA >> 2, c16 = cA & 3;
      int grow = row0 + rl;
      if (grow >= Mrows) grow = Mrows - 1;  // clamp tail; stores guarded
      async_ld16(A + (size_t)grow * strideA + kk + c16 * 8, &As[cbase * 8]);
      async_ld16(B + (size_t)(col0 + rl) * strideB + kk + c16 * 8, &Bs[cbase * 8]);
    }
    __syncthreads();

    v8bf af[4], bfr[4];
#pragma unroll
    for (int mt = 0; mt < 4; mt++) {
      int r = wm * 64 + mt * 16 + l16;
      af[mt] = *(const v8bf*)&As[r * 32 + quad * 8];
    }
#pragma unroll
    for (int nt = 0; nt < 4; nt++) {
      int n = wn * 64 + nt * 16 + l16;
      bfr[nt] = *(const v8bf*)&Bs[n * 32 + quad * 8];
    }
#pragma unroll
    for (int mt = 0; mt < 4; mt++)
#pragma unroll
      for (int nt = 0; nt < 4; nt++)
        acc[mt][nt] =
            __builtin_amdgcn_mfma_f32_16x16x32_bf16(af[mt], bfr[nt], acc[mt][nt], 0, 0, 0);
    __syncthreads();
  }

  // epilogue: C/D layout col=lane&15, row=quad*4+reg
  float pc0[4], pc1[4], bc[4];
#pragma unroll
  for (int nt = 0; nt < 4; nt++) {
    int gcol = col0 + wn * 64 + nt * 16 + l16;
    pc0[nt] = doepi ? p0[gcol] : 0.f;
    pc1[nt] = doepi ? p1[gcol] : 0.f;
    bc[nt] = doepi ? biasc[gcol] : 0.f;
  }
#pragma unroll
  for (int mt = 0; mt < 4; mt++)
#pragma unroll
    for (int r = 0; r < 4; r++) {
      int grow = row0 + wm * 64 + mt * 16 + quad * 4 + r;
      if (grow >= Mrows) continue;
      float m0v = 0.f, m1v = 0.f;
      if (doepi) { m0v = m0[grow]; m1v = m1[grow]; }
#pragma unroll
      for (int nt = 0; nt < 4; nt++) {
        int gcol = col0 + wn * 64 + nt * 16 + l16;
        size_t o = (size_t)grow * 256 + gcol;
        float v = acc[mt][nt][r];
        if (addprev) v += out[o];
        if (doepi) v += m0v * pc0[nt] + m1v * pc1[nt] + bc[nt];
        out[o] = v;
      }
    }
}

// ---------------------------------------------------------------------------
extern "C" void kernel_launch(void* const* d_in, const int* in_sizes, int n_in,
                              void* d_out, int out_size, void* d_ws, size_t ws_size,
                              hipStream_t stream) {
  const float* x = (const float*)d_in[0];
  const int* e00 = (const int*)d_in[1];
  const int* e01 = (const int*)d_in[2];
  const int* e10 = (const int*)d_in[3];
  const int* e11 = (const int*)d_in[4];
  const float* t0 = (const float*)d_in[5];
  const float* t1 = (const float*)d_in[6];
  const float* W1 = (const float*)d_in[7];
  const float* b1 = (const float*)d_in[8];
  const float* W2 = (const float*)d_in[9];
  const float* b2 = (const float*)d_in[10];
  const float* W3 = (const float*)d_in[11];
  const float* b3 = (const float*)d_in[12];
  const float* W4 = (const float*)d_in[13];
  const float* b4 = (const float*)d_in[14];
  const float* p0 = (const float*)d_in[15];
  const float* p1 = (const float*)d_in[16];
  const float* p2 = (const float*)d_in[17];
  const float* p3 = (const float*)d_in[18];
  const float* p4 = (const float*)d_in[19];
  const float* p5 = (const float*)d_in[20];
  float* out = (float*)d_out;

  int N = in_sizes[0] / 256;
  int E = in_sizes[1] / 2;
  int M4 = 4 * N;
  int nb = (M4 + 255) / 256;

  char* wp = (char*)d_ws;
  auto carve = [&](size_t bytes) {
    void* r = (void*)wp;
    wp += (bytes + 255) & ~(size_t)255;
    return r;
  };
  unsigned short* xb = (unsigned short*)carve((size_t)N * 256 * 2);
  unsigned short* Wt = (unsigned short*)carve((size_t)256 * 1024 * 2);
  int* hist = (int*)carve((size_t)M4 * 4);
  float* dis = (float*)carve((size_t)M4 * 4);
  int* rp = (int*)carve((size_t)M4 * 4);
  int* cursor = (int*)carve((size_t)M4 * 4);
  int* bsum = (int*)carve((size_t)nb * 4);
  float* biasc = (float*)carve(256 * 4);
  float* m0 = (float*)carve((size_t)N * 4);
  float* m1 = (float*)carve((size_t)N * 4);
  int2* payload = (int2*)carve((size_t)4 * E * 8);
  size_t used = (size_t)(wp - (char*)d_ws);
  size_t remain = (ws_size > used) ? ws_size - used : 0;
  bool fat = remain >= (size_t)N * 1024 * 2;
  unsigned short* Agg = (unsigned short*)wp;  // fat: N x 1024; lean: N x 256

  int gE = (E + 255) / 256;
  int gM = (M4 + 255) / 256;

  lc_zero<<<gM, 256, 0, stream>>>(hist, M4);
  lc_hist<<<dim3(gE, 4), 256, 0, stream>>>(e00, e01, e10, e11, hist, N, E);
  lc_dis<<<gM, 256, 0, stream>>>(hist, dis, M4);
  lc_scan1<<<nb, 256, 0, stream>>>(hist, rp, bsum, M4);
  lc_scan2<<<1, 256, 0, stream>>>(bsum, nb);
  lc_scan3<<<nb, 256, 0, stream>>>(rp, cursor, bsum, M4);
  lc_fill<<<dim3(gE, 4), 256, 0, stream>>>(e00, e01, e10, e11, cursor, dis, payload, N, E);
  lc_bias<<<1, 256, 0, stream>>>(b1, b2, b3, b4, p2, p3, p4, p5, biasc);
  lc_prep<<<1024, 256, 0, stream>>>(W1, W2, W3, W4, p2, p3, p4, p5, Wt);
  lc_cvt<<<(N * 64 + 255) / 256, 256, 0, stream>>>((const float4*)x, (ushort4*)xb,
                                                   t0, t1, m0, m1, N * 64);

  int gemm_mb = (N + 127) / 128;
  if (fat) {
    lc_aggx<<<N, 256, 0, stream>>>(xb, Agg, 1024, 4, 0, rp, hist, dis, payload, N);
    lc_gemm<<<dim3(gemm_mb, 2), 256, 0, stream>>>(Agg, 1024, Wt, 1024, 1024, out, N,
                                                  0, 1, m0, m1, p0, p1, biasc);
  } else {
    for (int k = 0; k < 4; k++) {
      lc_aggx<<<(N + 3) / 4, 256, 0, stream>>>(xb, Agg, 256, 1, k, rp, hist, dis,
                                               payload, N);
      lc_gemm<<<dim3(gemm_mb, 2), 256, 0, stream>>>(Agg, 256, Wt + k * 256, 1024, 256,
                                                    out, N, (k > 0) ? 1 : 0,
                                                    (k == 3) ? 1 : 0, m0, m1, p0, p1,
                                                    biasc);
    }
  }
}